// Round 1
// baseline (419.922 us; speedup 1.0000x reference)
//
#include <hip/hip_runtime.h>

// Dims (fixed by the reference): T=64, S=512, X=16, Y=16, G=64.
// Key simplifications (faithful to the reference semantics):
//  * Phi = trans @ V_pre with V_pre == zeros  ->  Phi == 0, `trans` unused.
//  * J = pi_0 @ V[0]  ->  only t=0 slices of px / py are live.
//  * cost[0,x,y] = x + y (MAX_CX = MAX_CY = LAM = 1).
// We still compute the full pi_0-weighted sum over all s (no one-hot shortcut).

#define S_ 512
#define X_ 16
#define Y_ 16
#define G_ 64

__launch_bounds__(256)
__global__ void mdp_kernel(const float* __restrict__ pv,
                           const float* __restrict__ obv,
                           const float* __restrict__ lt,
                           const float* __restrict__ pi0,
                           float* __restrict__ out) {
    __shared__ float px[X_];
    __shared__ float py[Y_][G_];      // py[y][g], col-softmax over y
    __shared__ float A[S_][Y_];       // 32 KB
    __shared__ float red[256];
    __shared__ float mx_sh;

    const int tid = threadIdx.x;

    // ---- Phase 1a: px = softmax(pv[0:16]); mx = E_px[x] ----
    if (tid == 0) {
        float e[X_], m = -1e30f;
        for (int x = 0; x < X_; ++x) { e[x] = pv[x]; m = fmaxf(m, e[x]); }
        float s = 0.f;
        for (int x = 0; x < X_; ++x) { e[x] = __expf(e[x] - m); s += e[x]; }
        const float inv = 1.f / s;
        float mx = 0.f;
        for (int x = 0; x < X_; ++x) { px[x] = e[x] * inv; mx += px[x] * (float)x; }
        mx_sh = mx;
    }
    // ---- Phase 1b: py[:,g] = softmax over y of pv[1024 + y*64 + g] ----
    if (tid < G_) {
        const int g = tid;
        float e[Y_], m = -1e30f;
        for (int y = 0; y < Y_; ++y) { e[y] = pv[1024 + y * G_ + g]; m = fmaxf(m, e[y]); }
        float s = 0.f;
        for (int y = 0; y < Y_; ++y) { e[y] = __expf(e[y] - m); s += e[y]; }
        const float inv = 1.f / s;
        for (int y = 0; y < Y_; ++y) py[y][g] = e[y] * inv;
    }
    __syncthreads();

    const float mx = mx_sh;

    // ---- Phase 2: A[s][y] = sum_x px[x]*lt[s,x,y] + mx + y ----
    for (int i = tid; i < S_ * Y_; i += 256) {
        const int s = i >> 4, y = i & 15;
        const float* row = lt + s * (X_ * Y_) + y;
        float a = 0.f;
        #pragma unroll
        for (int x = 0; x < X_; ++x) a += px[x] * row[x * Y_];
        A[s][y] = a + mx + (float)y;
    }
    __syncthreads();

    // ---- Phase 3: J = sum_{s,g} pi0[s]*obv[s,g]*(sum_y A[s,y]*py[y][g]) ----
    float acc = 0.f;
    for (int i = tid; i < S_ * G_; i += 256) {
        const int s = i >> 6, g = i & 63;
        float c = 0.f;
        #pragma unroll
        for (int y = 0; y < Y_; ++y) c += A[s][y] * py[y][g];
        acc += pi0[s] * obv[s * G_ + g] * c;
    }
    red[tid] = acc;
    __syncthreads();
    if (tid == 0) {
        float s = 0.f;
        for (int t = 0; t < 256; ++t) s += red[t];
        out[0] = s;
    }
}

extern "C" void kernel_launch(void* const* d_in, const int* in_sizes, int n_in,
                              void* d_out, int out_size, void* d_ws, size_t ws_size,
                              hipStream_t stream) {
    const float* pv  = (const float*)d_in[0];   // policy_var [66560]
    // d_in[1] = trans [512*512*16*16] — unused: Phi multiplies an all-zero V_pre.
    const float* obv = (const float*)d_in[2];   // [512,64]
    const float* lt  = (const float*)d_in[3];   // [512,16,16]
    const float* pi0 = (const float*)d_in[4];   // [512]
    float* out = (float*)d_out;

    mdp_kernel<<<dim3(1), dim3(256), 0, stream>>>(pv, obv, lt, pi0, out);
}

// Round 2
// 302.353 us; speedup vs baseline: 1.3888x; 1.3888x over previous
//
#include <hip/hip_runtime.h>

// Dims (fixed by the reference): T=64, S=512, X=16, Y=16, G=64.
// Semantics-faithful simplifications:
//  * Phi = trans @ V_pre with V_pre == zeros  ->  Phi == 0, `trans` unused.
//  * J = pi_0 @ V[0]  ->  only t=0 slices of px / py are live.
//  * cost[0,x,y] = x + y (MAX_CX = MAX_CY = LAM = 1).
// Full pi_0-weighted sum over all s retained (no one-hot shortcut).
//
// Structure: 128 partial-sum blocks (4 states each, deterministic order,
// no atomics) -> 128 partials in ws -> 1-wave finishing reduce.
// Every ws slot used is written every call (harness poisons ws with 0xAA).

#define S_ 512
#define X_ 16
#define Y_ 16
#define G_ 64
#define PV_Y_OFF 1024     // T*X = 64*16
#define NBLK 128
#define SPB (S_ / NBLK)   // 4 states per block

__launch_bounds__(256)
__global__ void mdp_partial(const float* __restrict__ pv,
                            const float* __restrict__ obv,
                            const float* __restrict__ lt,
                            const float* __restrict__ pi0,
                            float* __restrict__ partial) {
    __shared__ float px[X_];
    __shared__ float py[Y_][G_];
    __shared__ float A[SPB][Y_];
    __shared__ float red[256];
    __shared__ float mx_sh;

    const int tid = threadIdx.x;

    // px = softmax(pv[0:16]); mx = E_px[x]  (serial on lane 0 — 16 elems)
    if (tid == 0) {
        float e[X_], m = -1e30f;
        for (int x = 0; x < X_; ++x) { e[x] = pv[x]; m = fmaxf(m, e[x]); }
        float s = 0.f;
        for (int x = 0; x < X_; ++x) { e[x] = __expf(e[x] - m); s += e[x]; }
        const float inv = 1.f / s;
        float mx = 0.f;
        for (int x = 0; x < X_; ++x) { px[x] = e[x] * inv; mx += px[x] * (float)x; }
        mx_sh = mx;
    }
    // py[:,g] = softmax over y of pv[1024 + y*64 + g]  (one thread per column)
    if (tid < G_) {
        const int g = tid;
        float e[Y_], m = -1e30f;
        for (int y = 0; y < Y_; ++y) { e[y] = pv[PV_Y_OFF + y * G_ + g]; m = fmaxf(m, e[y]); }
        float s = 0.f;
        for (int y = 0; y < Y_; ++y) { e[y] = __expf(e[y] - m); s += e[y]; }
        const float inv = 1.f / s;
        for (int y = 0; y < Y_; ++y) py[y][g] = e[y] * inv;
    }
    __syncthreads();

    const int s0 = blockIdx.x * SPB;

    // A[sl][y] = sum_x px[x]*lt[s,x,y] + mx + y   (64 dot products, 64 threads)
    if (tid < SPB * Y_) {
        const int sl = tid >> 4, y = tid & 15;
        const float* row = lt + (s0 + sl) * (X_ * Y_) + y;
        float a = 0.f;
        #pragma unroll
        for (int x = 0; x < X_; ++x) a += px[x] * row[x * Y_];
        A[sl][y] = a + mx_sh + (float)y;
    }
    __syncthreads();

    // acc = pi0[s]*obv[s,g]*(sum_y A[sl,y]*py[y,g]) , one (s,g) per thread
    const int sl = tid >> 6, g = tid & 63;
    const int s = s0 + sl;
    float c = 0.f;
    #pragma unroll
    for (int y = 0; y < Y_; ++y) c += A[sl][y] * py[y][g];
    float acc = pi0[s] * obv[s * G_ + g] * c;

    red[tid] = acc;
    __syncthreads();
    #pragma unroll
    for (int off = 128; off > 0; off >>= 1) {
        if (tid < off) red[tid] += red[tid + off];
        __syncthreads();
    }
    if (tid == 0) partial[blockIdx.x] = red[0];
}

__launch_bounds__(64)
__global__ void mdp_final(const float* __restrict__ partial,
                          float* __restrict__ out) {
    const int tid = threadIdx.x;
    float v = partial[tid] + partial[tid + 64];
    #pragma unroll
    for (int off = 32; off > 0; off >>= 1) v += __shfl_down(v, off);
    if (tid == 0) out[0] = v;
}

extern "C" void kernel_launch(void* const* d_in, const int* in_sizes, int n_in,
                              void* d_out, int out_size, void* d_ws, size_t ws_size,
                              hipStream_t stream) {
    const float* pv  = (const float*)d_in[0];   // policy_var [66560]
    // d_in[1] = trans — unused (multiplies an all-zero V_pre).
    const float* obv = (const float*)d_in[2];   // [512,64]
    const float* lt  = (const float*)d_in[3];   // [512,16,16]
    const float* pi0 = (const float*)d_in[4];   // [512]
    float* out = (float*)d_out;
    float* partial = (float*)d_ws;              // 128 floats, all written each call

    mdp_partial<<<dim3(NBLK), dim3(256), 0, stream>>>(pv, obv, lt, pi0, partial);
    mdp_final<<<dim3(1), dim3(64), 0, stream>>>(partial, out);
}